// Round 5
// baseline (596.527 us; speedup 1.0000x reference)
//
#include <hip/hip_runtime.h>

#define NGRAPH 64
#define HDIM 128
#define POOL_RS 8
#define SLICES 8
#define SCOLS 16

// ---------------- zero int degree + pool accumulators ----------------
__global__ __launch_bounds__(256) void k_zero(int* deg, float* sums, int N) {
  int i = blockIdx.x * 256 + threadIdx.x;
  if (i < N) deg[i] = 0;
  if (i < NGRAPH * HDIM) sums[i] = 0.0f;
}

// ---------------- degree histogram over dst (int atomics) ----------------
__global__ __launch_bounds__(256) void k_hist(const int* __restrict__ ei, int* deg, int E) {
  int e = blockIdx.x * 256 + threadIdx.x;
  if (e < E) atomicAdd(&deg[ei[E + e]], 1);
}

// ---------------- scan pass 1: per-block exclusive scan of deg ----------------
__global__ __launch_bounds__(256) void k_scan1(const int* __restrict__ deg,
                                               int* __restrict__ rowptr,
                                               int* __restrict__ bsum, int N) {
  __shared__ int s[256];
  int tid = threadIdx.x;
  int i = blockIdx.x * 256 + tid;
  int v = (i < N) ? deg[i] : 0;
  s[tid] = v;
  __syncthreads();
#pragma unroll
  for (int off = 1; off < 256; off <<= 1) {
    int t = (tid >= off) ? s[tid - off] : 0;
    __syncthreads();
    s[tid] += t;
    __syncthreads();
  }
  if (i < N) rowptr[i] = s[tid] - v;       // exclusive
  if (tid == 255) bsum[blockIdx.x] = s[255];
}

// ---------------- scan pass 2: exclusive scan of block sums (single block) -------
__global__ __launch_bounds__(256) void k_scan2(int* __restrict__ bsum, int nb) {
  __shared__ int s[256];
  int tid = threadIdx.x;
  int v = (tid < nb) ? bsum[tid] : 0;
  s[tid] = v;
  __syncthreads();
#pragma unroll
  for (int off = 1; off < 256; off <<= 1) {
    int t = (tid >= off) ? s[tid - off] : 0;
    __syncthreads();
    s[tid] += t;
    __syncthreads();
  }
  if (tid < nb) bsum[tid] = s[tid] - v;    // exclusive
}

// ------- scan pass 3: add block offset; init cursor; dinv = rsqrt(deg+1) --------
__global__ __launch_bounds__(256) void k_scan3(const int* __restrict__ deg,
                                               int* __restrict__ rowptr,
                                               const int* __restrict__ bsum,
                                               int* __restrict__ cursor,
                                               float* __restrict__ dinv, int N, int E) {
  int i = blockIdx.x * 256 + threadIdx.x;
  if (i < N) {
    int r = rowptr[i] + bsum[i >> 8];
    rowptr[i] = r;
    cursor[i] = r;
    dinv[i] = rsqrtf((float)deg[i] + 1.0f);
  }
  if (i == 0) rowptr[N] = E;
}

// ---------------- CSR fill: col[pos] = src, sorted by dst ----------------
__global__ __launch_bounds__(256) void k_fill(const int* __restrict__ ei,
                                              int* __restrict__ cursor,
                                              int* __restrict__ col, int E) {
  int e = blockIdx.x * 256 + threadIdx.x;
  if (e < E) {
    int pos = atomicAdd(&cursor[ei[E + e]], 1);
    col[pos] = ei[e];
  }
}

// ------- graph boundaries from sorted batch ----------
__global__ __launch_bounds__(256) void k_gbound(const int* __restrict__ bat,
                                                int* __restrict__ gstart, int N) {
  int i = blockIdx.x * 256 + threadIdx.x;
  if (i >= N) return;
  int b = bat[i];
  int prev = (i == 0) ? -1 : bat[i - 1];
  for (int g = prev + 1; g <= b; ++g) gstart[g] = i;
  if (i == N - 1)
    for (int g = b + 1; g <= NGRAPH; ++g) gstart[g] = N;
}

// ------- C[N,128] = dinv[row] * (A[N,128] @ W[128,128])  (fp32, LDS-tiled) --------
__global__ __launch_bounds__(256) void k_gemm(const float* __restrict__ A,
                                              const float* __restrict__ W,
                                              const float* __restrict__ dinv,
                                              float* __restrict__ C, int N) {
  __shared__ float Ws[64][128];   // [k][col]
  __shared__ float As[64][64];    // [k][row]
  const int tid = threadIdx.x;
  const int tx = tid & 31;
  const int ty = tid >> 5;
  const int row0 = blockIdx.x * 64;

  float acc[8][4];
#pragma unroll
  for (int i = 0; i < 8; ++i)
#pragma unroll
    for (int j = 0; j < 4; ++j) acc[i][j] = 0.0f;

  for (int kc = 0; kc < 2; ++kc) {
#pragma unroll
    for (int i = 0; i < 8; ++i) {
      int flat = tid + i * 256;
      int k = flat >> 5;
      int c4 = (flat & 31) * 4;
      *(float4*)&Ws[k][c4] = *(const float4*)&W[(kc * 64 + k) * 128 + c4];
    }
#pragma unroll
    for (int i = 0; i < 4; ++i) {
      int flat = tid + i * 256;
      int r = flat & 63;
      int kq = (flat >> 6) * 4;
      int row = row0 + r;
      float4 a;
      if (row < N) a = *(const float4*)&A[row * 128 + kc * 64 + kq];
      else { a.x = a.y = a.z = a.w = 0.0f; }
      As[kq + 0][r] = a.x;
      As[kq + 1][r] = a.y;
      As[kq + 2][r] = a.z;
      As[kq + 3][r] = a.w;
    }
    __syncthreads();
#pragma unroll
    for (int k = 0; k < 64; ++k) {
      float4 w = *(float4*)&Ws[k][tx * 4];
      float4 alo = *(float4*)&As[k][ty * 8];
      float4 ahi = *(float4*)&As[k][ty * 8 + 4];
      float av[8] = {alo.x, alo.y, alo.z, alo.w, ahi.x, ahi.y, ahi.z, ahi.w};
#pragma unroll
      for (int i = 0; i < 8; ++i) {
        acc[i][0] = fmaf(av[i], w.x, acc[i][0]);
        acc[i][1] = fmaf(av[i], w.y, acc[i][1]);
        acc[i][2] = fmaf(av[i], w.z, acc[i][2]);
        acc[i][3] = fmaf(av[i], w.w, acc[i][3]);
      }
    }
    __syncthreads();
  }
#pragma unroll
  for (int i = 0; i < 8; ++i) {
    int row = row0 + ty * 8 + i;
    if (row < N) {
      float dn = dinv[row];
      float4 o;
      o.x = acc[i][0] * dn; o.y = acc[i][1] * dn;
      o.z = acc[i][2] * dn; o.w = acc[i][3] * dn;
      *(float4*)&C[row * 128 + tx * 4] = o;
    }
  }
}

// ------- column-sliced gather: h[n,c] = relu(dinv[n]*(xws[n,c]+sum_src xws[src,c])+b[c])
// slice = blockIdx.x & 7 (XCD-pinned via round-robin dispatch); 16 cols/slice.
// 256 threads = 64 nodes x 4 lanes; lane owns float4 of the slice.
__global__ __launch_bounds__(256) void k_gslice(const int* __restrict__ rowptr,
                                                const int* __restrict__ col,
                                                const float* __restrict__ xws,
                                                const float* __restrict__ dinv,
                                                const float* __restrict__ b,
                                                float* __restrict__ h, int N) {
  int slice = blockIdx.x & (SLICES - 1);
  int widx  = blockIdx.x >> 3;
  int g = threadIdx.x >> 2;          // node group 0..63
  int l = threadIdx.x & 3;           // lane in group
  int node = widx * 64 + g;
  if (node >= N) return;
  int c = slice * SCOLS + l * 4;

  int beg = rowptr[node], end = rowptr[node + 1];
  float4 acc; acc.x = acc.y = acc.z = acc.w = 0.0f;

  for (int e = beg; e < end; e += 4) {
    int ce = -1;
    if (e + l < end) ce = __builtin_nontemporal_load(&col[e + l]);
#pragma unroll
    for (int j = 0; j < 4; ++j) {
      int s = __shfl(ce, j, 4);
      if (e + j < end) {
        float4 v = *(const float4*)&xws[(size_t)s * 128 + c];
        acc.x += v.x; acc.y += v.y; acc.z += v.z; acc.w += v.w;
      }
    }
  }
  float dn = dinv[node];
  float4 self = *(const float4*)&xws[(size_t)node * 128 + c];
  float4 o;
  o.x = fmaxf(fmaf(dn, acc.x + self.x, 0.0f) + b[c + 0], 0.0f);
  o.y = fmaxf(fmaf(dn, acc.y + self.y, 0.0f) + b[c + 1], 0.0f);
  o.z = fmaxf(fmaf(dn, acc.z + self.z, 0.0f) + b[c + 2], 0.0f);
  o.w = fmaxf(fmaf(dn, acc.w + self.w, 0.0f) + b[c + 3], 0.0f);
  *(float4*)&h[(size_t)node * 128 + c] = o;
}

// ------- segmented mean-pool: grid (NGRAPH, POOL_RS); register + LDS reduce -------
__global__ __launch_bounds__(256) void k_pool(const float* __restrict__ h,
                                              const int* __restrict__ gstart,
                                              float* __restrict__ sums) {
  int g = blockIdx.x;
  int rs = blockIdx.y;
  int beg = gstart[g], end = gstart[g + 1];
  int tid = threadIdx.x;
  int ty = tid >> 5;            // 8 row groups
  int q = (tid & 31) * 4;       // col quad

  float4 acc; acc.x = acc.y = acc.z = acc.w = 0.0f;
  for (int r = beg + rs * 8 + ty; r < end; r += POOL_RS * 8) {
    float4 v = *(const float4*)&h[(size_t)r * 128 + q];
    acc.x += v.x; acc.y += v.y; acc.z += v.z; acc.w += v.w;
  }
  __shared__ float s[8][128];
  *(float4*)&s[ty][q] = acc;
  __syncthreads();
  if (tid < 32) {
    int qq = tid * 4;
    float4 t; t.x = t.y = t.z = t.w = 0.0f;
#pragma unroll
    for (int j = 0; j < 8; ++j) {
      float4 v = *(float4*)&s[j][qq];
      t.x += v.x; t.y += v.y; t.z += v.z; t.w += v.w;
    }
    float* base = &sums[g * 128 + qq];
    unsafeAtomicAdd(base + 0, t.x);
    unsafeAtomicAdd(base + 1, t.y);
    unsafeAtomicAdd(base + 2, t.z);
    unsafeAtomicAdd(base + 3, t.w);
  }
}

// ---------------- head: out[g,c] = (sums[g]/max(cnt,1)) @ Wc + bc ----------------
__global__ __launch_bounds__(640) void k_head(const float* __restrict__ sums,
                                              const int* __restrict__ gstart,
                                              const float* __restrict__ Wc,
                                              const float* __restrict__ bc,
                                              float* __restrict__ out) {
  int t = threadIdx.x;
  int g = t / 10, c = t % 10;
  float cntf = (float)(gstart[g + 1] - gstart[g]);
  float inv = 1.0f / fmaxf(cntf, 1.0f);
  float acc = 0.0f;
  for (int h = 0; h < 128; ++h)
    acc = fmaf(sums[g * 128 + h], Wc[h * 10 + c], acc);
  out[t] = acc * inv + bc[c];
}

extern "C" void kernel_launch(void* const* d_in, const int* in_sizes, int n_in,
                              void* d_out, int out_size, void* d_ws, size_t ws_size,
                              hipStream_t stream) {
  const float* x   = (const float*)d_in[0];
  const int*   ei  = (const int*)d_in[1];
  const int*   bat = (const int*)d_in[2];
  const float* W1  = (const float*)d_in[3];
  const float* b1  = (const float*)d_in[4];
  const float* W2  = (const float*)d_in[5];
  const float* b2  = (const float*)d_in[6];
  const float* W3  = (const float*)d_in[7];
  const float* b3  = (const float*)d_in[8];
  const float* Wc  = (const float*)d_in[9];
  const float* bc  = (const float*)d_in[10];

  const int N = in_sizes[0] / 128;
  const int E = in_sizes[1] / 2;

  // workspace layout
  char* wsb = (char*)d_ws;
  int*   deg    = (int*)wsb;                      wsb += (size_t)N * 4;
  int*   rowptr = (int*)wsb;                      wsb += (size_t)(N + 1) * 4;
  int*   cursor = (int*)wsb;                      wsb += (size_t)N * 4;
  int*   bsum   = (int*)wsb;                      wsb += 256 * 4;
  float* dinv   = (float*)wsb;                    wsb += (size_t)N * 4;
  int*   col    = (int*)wsb;                      wsb += (size_t)E * 4;
  float* sums   = (float*)wsb;                    wsb += NGRAPH * HDIM * 4;
  int*   gstart = (int*)wsb;                      wsb += (NGRAPH + 1) * 4;
  wsb = (char*)(((size_t)wsb + 255) & ~(size_t)255);
  float* B1     = (float*)wsb;                    wsb += (size_t)N * 128 * 4;
  float* B2     = (float*)wsb;

  const int nb_N   = (N + 255) / 256;
  const int nb_E   = (E + 255) / 256;
  const int nb_gem = (N + 63) / 64;
  const int nb_gsl = ((N + 63) / 64) * SLICES;

  // CSR build (once per call, reused for all 3 layers)
  k_zero<<<nb_N, 256, 0, stream>>>(deg, sums, N);
  k_hist<<<nb_E, 256, 0, stream>>>(ei, deg, E);
  k_scan1<<<nb_N, 256, 0, stream>>>(deg, rowptr, bsum, N);
  k_scan2<<<1, 256, 0, stream>>>(bsum, nb_N);
  k_scan3<<<nb_N, 256, 0, stream>>>(deg, rowptr, bsum, cursor, dinv, N, E);
  k_fill<<<nb_E, 256, 0, stream>>>(ei, cursor, col, E);
  k_gbound<<<nb_N, 256, 0, stream>>>(bat, gstart, N);

  const float* in_ptr = x;
  const float* Wl[3] = {W1, W2, W3};
  const float* bl[3] = {b1, b2, b3};
  for (int L = 0; L < 3; ++L) {
    k_gemm<<<nb_gem, 256, 0, stream>>>(in_ptr, Wl[L], dinv, B1, N);
    k_gslice<<<nb_gsl, 256, 0, stream>>>(rowptr, col, B1, dinv, bl[L], B2, N);
    in_ptr = B2;
  }

  dim3 pgrid(NGRAPH, POOL_RS);
  k_pool<<<pgrid, 256, 0, stream>>>(B2, gstart, sums);
  k_head<<<1, 640, 0, stream>>>(sums, gstart, Wc, bc, (float*)d_out);
}

// Round 6
// 462.814 us; speedup vs baseline: 1.2889x; 1.2889x over previous
//
#include <hip/hip_runtime.h>

#define NGRAPH 64
#define HDIM 128
#define POOL_RS 8

typedef _Float16 h2v __attribute__((ext_vector_type(2)));
typedef _Float16 h4v __attribute__((ext_vector_type(4)));

// ---------------- zero int degree + pool accumulators ----------------
__global__ __launch_bounds__(256) void k_zero(int* deg, float* sums, int N) {
  int i = blockIdx.x * 256 + threadIdx.x;
  if (i < N) deg[i] = 0;
  if (i < NGRAPH * HDIM) sums[i] = 0.0f;
}

// ---------------- degree histogram over dst (int atomics) ----------------
__global__ __launch_bounds__(256) void k_hist(const int* __restrict__ ei, int* deg, int E) {
  int e = blockIdx.x * 256 + threadIdx.x;
  if (e < E) atomicAdd(&deg[ei[E + e]], 1);
}

// ---------------- scan pass 1: per-block exclusive scan of deg ----------------
__global__ __launch_bounds__(256) void k_scan1(const int* __restrict__ deg,
                                               int* __restrict__ rowptr,
                                               int* __restrict__ bsum, int N) {
  __shared__ int s[256];
  int tid = threadIdx.x;
  int i = blockIdx.x * 256 + tid;
  int v = (i < N) ? deg[i] : 0;
  s[tid] = v;
  __syncthreads();
#pragma unroll
  for (int off = 1; off < 256; off <<= 1) {
    int t = (tid >= off) ? s[tid - off] : 0;
    __syncthreads();
    s[tid] += t;
    __syncthreads();
  }
  if (i < N) rowptr[i] = s[tid] - v;       // exclusive
  if (tid == 255) bsum[blockIdx.x] = s[255];
}

// ---------------- scan pass 2: exclusive scan of block sums (single block) -------
__global__ __launch_bounds__(256) void k_scan2(int* __restrict__ bsum, int nb) {
  __shared__ int s[256];
  int tid = threadIdx.x;
  int v = (tid < nb) ? bsum[tid] : 0;
  s[tid] = v;
  __syncthreads();
#pragma unroll
  for (int off = 1; off < 256; off <<= 1) {
    int t = (tid >= off) ? s[tid - off] : 0;
    __syncthreads();
    s[tid] += t;
    __syncthreads();
  }
  if (tid < nb) bsum[tid] = s[tid] - v;    // exclusive
}

// ------- scan pass 3: add block offset; init cursor; dinv = rsqrt(deg+1) --------
__global__ __launch_bounds__(256) void k_scan3(const int* __restrict__ deg,
                                               int* __restrict__ rowptr,
                                               const int* __restrict__ bsum,
                                               int* __restrict__ cursor,
                                               float* __restrict__ dinv, int N, int E) {
  int i = blockIdx.x * 256 + threadIdx.x;
  if (i < N) {
    int r = rowptr[i] + bsum[i >> 8];
    rowptr[i] = r;
    cursor[i] = r;
    dinv[i] = rsqrtf((float)deg[i] + 1.0f);
  }
  if (i == 0) rowptr[N] = E;
}

// ---------------- CSR fill: col[pos] = src, sorted by dst ----------------
__global__ __launch_bounds__(256) void k_fill(const int* __restrict__ ei,
                                              int* __restrict__ cursor,
                                              int* __restrict__ col, int E) {
  int e = blockIdx.x * 256 + threadIdx.x;
  if (e < E) {
    int pos = atomicAdd(&cursor[ei[E + e]], 1);
    col[pos] = ei[e];
  }
}

// ------- graph boundaries from sorted batch ----------
__global__ __launch_bounds__(256) void k_gbound(const int* __restrict__ bat,
                                                int* __restrict__ gstart, int N) {
  int i = blockIdx.x * 256 + threadIdx.x;
  if (i >= N) return;
  int b = bat[i];
  int prev = (i == 0) ? -1 : bat[i - 1];
  for (int g = prev + 1; g <= b; ++g) gstart[g] = i;
  if (i == N - 1)
    for (int g = b + 1; g <= NGRAPH; ++g) gstart[g] = N;
}

// ------- C[N,128](fp16) = dinv[row] * (A[N,128] @ W[128,128])  (fp32 compute) -----
__global__ __launch_bounds__(256) void k_gemm(const float* __restrict__ A,
                                              const float* __restrict__ W,
                                              const float* __restrict__ dinv,
                                              _Float16* __restrict__ C, int N) {
  __shared__ float Ws[64][128];   // [k][col]
  __shared__ float As[64][64];    // [k][row]
  const int tid = threadIdx.x;
  const int tx = tid & 31;
  const int ty = tid >> 5;
  const int row0 = blockIdx.x * 64;

  float acc[8][4];
#pragma unroll
  for (int i = 0; i < 8; ++i)
#pragma unroll
    for (int j = 0; j < 4; ++j) acc[i][j] = 0.0f;

  for (int kc = 0; kc < 2; ++kc) {
#pragma unroll
    for (int i = 0; i < 8; ++i) {
      int flat = tid + i * 256;
      int k = flat >> 5;
      int c4 = (flat & 31) * 4;
      *(float4*)&Ws[k][c4] = *(const float4*)&W[(kc * 64 + k) * 128 + c4];
    }
#pragma unroll
    for (int i = 0; i < 4; ++i) {
      int flat = tid + i * 256;
      int r = flat & 63;
      int kq = (flat >> 6) * 4;
      int row = row0 + r;
      float4 a;
      if (row < N) a = *(const float4*)&A[row * 128 + kc * 64 + kq];
      else { a.x = a.y = a.z = a.w = 0.0f; }
      As[kq + 0][r] = a.x;
      As[kq + 1][r] = a.y;
      As[kq + 2][r] = a.z;
      As[kq + 3][r] = a.w;
    }
    __syncthreads();
#pragma unroll
    for (int k = 0; k < 64; ++k) {
      float4 w = *(float4*)&Ws[k][tx * 4];
      float4 alo = *(float4*)&As[k][ty * 8];
      float4 ahi = *(float4*)&As[k][ty * 8 + 4];
      float av[8] = {alo.x, alo.y, alo.z, alo.w, ahi.x, ahi.y, ahi.z, ahi.w};
#pragma unroll
      for (int i = 0; i < 8; ++i) {
        acc[i][0] = fmaf(av[i], w.x, acc[i][0]);
        acc[i][1] = fmaf(av[i], w.y, acc[i][1]);
        acc[i][2] = fmaf(av[i], w.z, acc[i][2]);
        acc[i][3] = fmaf(av[i], w.w, acc[i][3]);
      }
    }
    __syncthreads();
  }
#pragma unroll
  for (int i = 0; i < 8; ++i) {
    int row = row0 + ty * 8 + i;
    if (row < N) {
      float dn = dinv[row];
      h4v o;
      o[0] = (_Float16)(acc[i][0] * dn);
      o[1] = (_Float16)(acc[i][1] * dn);
      o[2] = (_Float16)(acc[i][2] * dn);
      o[3] = (_Float16)(acc[i][3] * dn);
      *(h4v*)&C[(size_t)row * 128 + tx * 4] = o;
    }
  }
}

// -------- fused gather (fp16 operand): h[n] = relu(dinv[n]*(xws[n]+sum xws[src])+b)
// one wave per node, lane owns 2 columns, 4 waves per block
__global__ __launch_bounds__(256) void k_gather(const int* __restrict__ rowptr,
                                                const int* __restrict__ col,
                                                const _Float16* __restrict__ xws,
                                                const float* __restrict__ dinv,
                                                const float* __restrict__ b,
                                                float* __restrict__ h, int N) {
  int node = blockIdx.x * 4 + (threadIdx.x >> 6);
  if (node >= N) return;
  int lane = threadIdx.x & 63;
  int c = lane * 2;
  int beg = rowptr[node], end = rowptr[node + 1];

  float ax = 0.0f, ay = 0.0f;
  int e = beg;
  for (; e + 1 < end; e += 2) {
    int s0 = col[e], s1 = col[e + 1];
    h2v v0 = *(const h2v*)&xws[(size_t)s0 * 128 + c];
    h2v v1 = *(const h2v*)&xws[(size_t)s1 * 128 + c];
    ax += (float)v0[0] + (float)v1[0];
    ay += (float)v0[1] + (float)v1[1];
  }
  if (e < end) {
    int s0 = col[e];
    h2v v0 = *(const h2v*)&xws[(size_t)s0 * 128 + c];
    ax += (float)v0[0];
    ay += (float)v0[1];
  }
  float dn = dinv[node];
  h2v self = *(const h2v*)&xws[(size_t)node * 128 + c];
  ax = (ax + (float)self[0]) * dn;
  ay = (ay + (float)self[1]) * dn;
  float2 o;
  o.x = fmaxf(ax + b[c], 0.0f);
  o.y = fmaxf(ay + b[c + 1], 0.0f);
  *(float2*)&h[(size_t)node * 128 + c] = o;
}

// ------- segmented mean-pool: grid (NGRAPH, POOL_RS); register + LDS reduce -------
__global__ __launch_bounds__(256) void k_pool(const float* __restrict__ h,
                                              const int* __restrict__ gstart,
                                              float* __restrict__ sums) {
  int g = blockIdx.x;
  int rs = blockIdx.y;
  int beg = gstart[g], end = gstart[g + 1];
  int tid = threadIdx.x;
  int ty = tid >> 5;            // 8 row groups
  int q = (tid & 31) * 4;       // col quad

  float4 acc; acc.x = acc.y = acc.z = acc.w = 0.0f;
  for (int r = beg + rs * 8 + ty; r < end; r += POOL_RS * 8) {
    float4 v = *(const float4*)&h[(size_t)r * 128 + q];
    acc.x += v.x; acc.y += v.y; acc.z += v.z; acc.w += v.w;
  }
  __shared__ float s[8][128];
  *(float4*)&s[ty][q] = acc;
  __syncthreads();
  if (tid < 32) {
    int qq = tid * 4;
    float4 t; t.x = t.y = t.z = t.w = 0.0f;
#pragma unroll
    for (int j = 0; j < 8; ++j) {
      float4 v = *(float4*)&s[j][qq];
      t.x += v.x; t.y += v.y; t.z += v.z; t.w += v.w;
    }
    float* base = &sums[g * 128 + qq];
    unsafeAtomicAdd(base + 0, t.x);
    unsafeAtomicAdd(base + 1, t.y);
    unsafeAtomicAdd(base + 2, t.z);
    unsafeAtomicAdd(base + 3, t.w);
  }
}

// ---------------- head: out[g,c] = (sums[g]/max(cnt,1)) @ Wc + bc ----------------
__global__ __launch_bounds__(640) void k_head(const float* __restrict__ sums,
                                              const int* __restrict__ gstart,
                                              const float* __restrict__ Wc,
                                              const float* __restrict__ bc,
                                              float* __restrict__ out) {
  int t = threadIdx.x;
  int g = t / 10, c = t % 10;
  float cntf = (float)(gstart[g + 1] - gstart[g]);
  float inv = 1.0f / fmaxf(cntf, 1.0f);
  float acc = 0.0f;
  for (int h = 0; h < 128; ++h)
    acc = fmaf(sums[g * 128 + h], Wc[h * 10 + c], acc);
  out[t] = acc * inv + bc[c];
}

extern "C" void kernel_launch(void* const* d_in, const int* in_sizes, int n_in,
                              void* d_out, int out_size, void* d_ws, size_t ws_size,
                              hipStream_t stream) {
  const float* x   = (const float*)d_in[0];
  const int*   ei  = (const int*)d_in[1];
  const int*   bat = (const int*)d_in[2];
  const float* W1  = (const float*)d_in[3];
  const float* b1  = (const float*)d_in[4];
  const float* W2  = (const float*)d_in[5];
  const float* b2  = (const float*)d_in[6];
  const float* W3  = (const float*)d_in[7];
  const float* b3  = (const float*)d_in[8];
  const float* Wc  = (const float*)d_in[9];
  const float* bc  = (const float*)d_in[10];

  const int N = in_sizes[0] / 128;
  const int E = in_sizes[1] / 2;

  // workspace layout
  char* wsb = (char*)d_ws;
  int*   deg    = (int*)wsb;                      wsb += (size_t)N * 4;
  int*   rowptr = (int*)wsb;                      wsb += (size_t)(N + 1) * 4;
  int*   cursor = (int*)wsb;                      wsb += (size_t)N * 4;
  int*   bsum   = (int*)wsb;                      wsb += 256 * 4;
  float* dinv   = (float*)wsb;                    wsb += (size_t)N * 4;
  int*   col    = (int*)wsb;                      wsb += (size_t)E * 4;
  float* sums   = (float*)wsb;                    wsb += NGRAPH * HDIM * 4;
  int*   gstart = (int*)wsb;                      wsb += (NGRAPH + 1) * 4;
  wsb = (char*)(((size_t)wsb + 255) & ~(size_t)255);
  _Float16* B1  = (_Float16*)wsb;                 wsb += (size_t)N * 128 * 2;
  wsb = (char*)(((size_t)wsb + 255) & ~(size_t)255);
  float* B2     = (float*)wsb;

  const int nb_N   = (N + 255) / 256;
  const int nb_E   = (E + 255) / 256;
  const int nb_gem = (N + 63) / 64;
  const int nb_gat = (N + 3) / 4;

  // CSR build (once per call, reused for all 3 layers)
  k_zero<<<nb_N, 256, 0, stream>>>(deg, sums, N);
  k_hist<<<nb_E, 256, 0, stream>>>(ei, deg, E);
  k_scan1<<<nb_N, 256, 0, stream>>>(deg, rowptr, bsum, N);
  k_scan2<<<1, 256, 0, stream>>>(bsum, nb_N);
  k_scan3<<<nb_N, 256, 0, stream>>>(deg, rowptr, bsum, cursor, dinv, N, E);
  k_fill<<<nb_E, 256, 0, stream>>>(ei, cursor, col, E);
  k_gbound<<<nb_N, 256, 0, stream>>>(bat, gstart, N);

  const float* in_ptr = x;
  const float* Wl[3] = {W1, W2, W3};
  const float* bl[3] = {b1, b2, b3};
  for (int L = 0; L < 3; ++L) {
    k_gemm<<<nb_gem, 256, 0, stream>>>(in_ptr, Wl[L], dinv, B1, N);
    k_gather<<<nb_gat, 256, 0, stream>>>(rowptr, col, B1, dinv, bl[L], B2, N);
    in_ptr = B2;
  }

  dim3 pgrid(NGRAPH, POOL_RS);
  k_pool<<<pgrid, 256, 0, stream>>>(B2, gstart, sums);
  k_head<<<1, 640, 0, stream>>>(sums, gstart, Wc, bc, (float*)d_out);
}

// Round 9
// 394.110 us; speedup vs baseline: 1.5136x; 1.1743x over previous
//
#include <hip/hip_runtime.h>

#define NGRAPH 64
#define HDIM 128
#define POOL_RS 8

typedef _Float16 h2 __attribute__((ext_vector_type(2)));
typedef _Float16 h4 __attribute__((ext_vector_type(4)));
typedef _Float16 h8 __attribute__((ext_vector_type(8)));
typedef float    f4 __attribute__((ext_vector_type(4)));

// ---------------- zero int degree + pool accumulators ----------------
__global__ __launch_bounds__(256) void k_zero(int* deg, float* sums, int N) {
  int i = blockIdx.x * 256 + threadIdx.x;
  if (i < N) deg[i] = 0;
  if (i < NGRAPH * HDIM) sums[i] = 0.0f;
}

// ---------------- degree histogram over dst (int atomics) ----------------
__global__ __launch_bounds__(256) void k_hist(const int* __restrict__ ei, int* deg, int E) {
  int e = blockIdx.x * 256 + threadIdx.x;
  if (e < E) atomicAdd(&deg[ei[E + e]], 1);
}

// ---------------- scan pass 1 ----------------
__global__ __launch_bounds__(256) void k_scan1(const int* __restrict__ deg,
                                               int* __restrict__ rowptr,
                                               int* __restrict__ bsum, int N) {
  __shared__ int s[256];
  int tid = threadIdx.x;
  int i = blockIdx.x * 256 + tid;
  int v = (i < N) ? deg[i] : 0;
  s[tid] = v;
  __syncthreads();
#pragma unroll
  for (int off = 1; off < 256; off <<= 1) {
    int t = (tid >= off) ? s[tid - off] : 0;
    __syncthreads();
    s[tid] += t;
    __syncthreads();
  }
  if (i < N) rowptr[i] = s[tid] - v;
  if (tid == 255) bsum[blockIdx.x] = s[255];
}

// ---------------- scan pass 2 ----------------
__global__ __launch_bounds__(256) void k_scan2(int* __restrict__ bsum, int nb) {
  __shared__ int s[256];
  int tid = threadIdx.x;
  int v = (tid < nb) ? bsum[tid] : 0;
  s[tid] = v;
  __syncthreads();
#pragma unroll
  for (int off = 1; off < 256; off <<= 1) {
    int t = (tid >= off) ? s[tid - off] : 0;
    __syncthreads();
    s[tid] += t;
    __syncthreads();
  }
  if (tid < nb) bsum[tid] = s[tid] - v;
}

// ------- scan pass 3: finalize rowptr; init cursor; dinv = rsqrt(deg+1) --------
__global__ __launch_bounds__(256) void k_scan3(const int* __restrict__ deg,
                                               int* __restrict__ rowptr,
                                               const int* __restrict__ bsum,
                                               int* __restrict__ cursor,
                                               float* __restrict__ dinv, int N, int E) {
  int i = blockIdx.x * 256 + threadIdx.x;
  if (i < N) {
    int r = rowptr[i] + bsum[i >> 8];
    rowptr[i] = r;
    cursor[i] = r;
    dinv[i] = rsqrtf((float)deg[i] + 1.0f);
  }
  if (i == 0) rowptr[N] = E;
}

// ---------------- CSR fill ----------------
__global__ __launch_bounds__(256) void k_fill(const int* __restrict__ ei,
                                              int* __restrict__ cursor,
                                              int* __restrict__ col, int E) {
  int e = blockIdx.x * 256 + threadIdx.x;
  if (e < E) {
    int pos = atomicAdd(&cursor[ei[E + e]], 1);
    col[pos] = ei[e];
  }
}

// ------- graph boundaries from sorted batch ----------
__global__ __launch_bounds__(256) void k_gbound(const int* __restrict__ bat,
                                                int* __restrict__ gstart, int N) {
  int i = blockIdx.x * 256 + threadIdx.x;
  if (i >= N) return;
  int b = bat[i];
  int prev = (i == 0) ? -1 : bat[i - 1];
  for (int g = prev + 1; g <= b; ++g) gstart[g] = i;
  if (i == N - 1)
    for (int g = b + 1; g <= NGRAPH; ++g) gstart[g] = N;
}

// ------- transpose+convert 3 weights: Wt[l][n][k] = fp16(W_l[k][n]) ----------
__global__ __launch_bounds__(256) void k_wt(const float* __restrict__ W1,
                                            const float* __restrict__ W2,
                                            const float* __restrict__ W3,
                                            _Float16* __restrict__ Wt) {
  int t = blockIdx.x * 256 + threadIdx.x;        // 0..49151
  if (t >= 3 * 16384) return;
  int l = t >> 14;
  int i = t & 16383;
  int k = i >> 7, n = i & 127;
  const float* W = (l == 0) ? W1 : (l == 1) ? W2 : W3;
  Wt[l * 16384 + n * 128 + k] = (_Float16)W[k * 128 + n];
}

// ------- convert x (fp32) -> xh (fp16) ----------
__global__ __launch_bounds__(256) void k_xh(const float* __restrict__ x,
                                            _Float16* __restrict__ xh, int N) {
  int t = blockIdx.x * 256 + threadIdx.x;
  if (t >= N * 32) return;
  float4 v = *(const float4*)&x[(size_t)t * 4];
  h4 o;
  o[0] = (_Float16)v.x; o[1] = (_Float16)v.y;
  o[2] = (_Float16)v.z; o[3] = (_Float16)v.w;
  *(h4*)&xh[(size_t)t * 4] = o;
}

// ------- MFMA GEMM: C[N,128](fp16) = dinv[row]*(A[N,128](fp16) @ W[128,128]) -------
// block = 256 thr = 4 waves, 128 rows/block (wave: 2 m-tiles of 16 rows).
// B staged from pre-transposed Wt[n][k] into LDS (row stride 136 to break conflicts).
__global__ __launch_bounds__(256) void k_mfma(const _Float16* __restrict__ A,
                                              const _Float16* __restrict__ Wt,
                                              const float* __restrict__ dinv,
                                              _Float16* __restrict__ C, int N) {
  __shared__ _Float16 ws[128 * 136];
  const int tid = threadIdx.x;
  // stage 128 rows x 128 halves = 2048 16B-chunks; 16 chunks per row
#pragma unroll
  for (int i = 0; i < 8; ++i) {
    int c0 = tid + i * 256;              // chunk id 0..2047
    int r = c0 >> 4;                     // row 0..127
    int off = (c0 & 15) * 8;             // half-offset 0..120
    *(h8*)&ws[r * 136 + off] = *(const h8*)&Wt[r * 128 + off];
  }
  __syncthreads();

  const int wv = tid >> 6, l = tid & 63;
  const int lm = l & 15, q = l >> 4;
  const int rb = blockIdx.x * 128 + wv * 32;

  h8 af[2][4];
#pragma unroll
  for (int mt = 0; mt < 2; ++mt) {
    const _Float16* Ap = &A[(size_t)(rb + mt * 16 + lm) * 128];
#pragma unroll
    for (int kc = 0; kc < 4; ++kc)
      af[mt][kc] = *(const h8*)&Ap[kc * 32 + q * 8];
  }

  f4 acc[2][8];
#pragma unroll
  for (int mt = 0; mt < 2; ++mt)
#pragma unroll
    for (int ct = 0; ct < 8; ++ct)
      acc[mt][ct] = (f4){0.0f, 0.0f, 0.0f, 0.0f};

#pragma unroll
  for (int ct = 0; ct < 8; ++ct) {
    h8 bf[4];
#pragma unroll
    for (int kc = 0; kc < 4; ++kc)
      bf[kc] = *(const h8*)&ws[(ct * 16 + lm) * 136 + kc * 32 + q * 8];
#pragma unroll
    for (int mt = 0; mt < 2; ++mt)
#pragma unroll
      for (int kc = 0; kc < 4; ++kc)
        acc[mt][ct] = __builtin_amdgcn_mfma_f32_16x16x32_f16(af[mt][kc], bf[kc],
                                                             acc[mt][ct], 0, 0, 0);
  }

#pragma unroll
  for (int mt = 0; mt < 2; ++mt) {
#pragma unroll
    for (int r = 0; r < 4; ++r) {
      int row = rb + mt * 16 + q * 4 + r;
      if (row < N) {
        float dn = dinv[row];
        _Float16* Cp = &C[(size_t)row * 128 + lm];
#pragma unroll
        for (int ct = 0; ct < 8; ++ct)
          Cp[ct * 16] = (_Float16)(acc[mt][ct][r] * dn);
      }
    }
  }
}

// -------- fused gather (fp16 in/out): h[n] = relu(dinv[n]*(xws[n]+sum xws[src])+b)
// half-wave (32 lanes) per node, lane owns 4 cols (8B loads); 8 nodes/block.
__global__ __launch_bounds__(256) void k_gather(const int* __restrict__ rowptr,
                                                const int* __restrict__ col,
                                                const _Float16* __restrict__ xws,
                                                const float* __restrict__ dinv,
                                                const float* __restrict__ b,
                                                _Float16* __restrict__ h, int N) {
  int node = blockIdx.x * 8 + (threadIdx.x >> 5);
  if (node >= N) return;
  int sl = threadIdx.x & 31;
  int c = sl * 4;
  int beg = rowptr[node], end = rowptr[node + 1];

  float a0 = 0.0f, a1 = 0.0f, a2 = 0.0f, a3 = 0.0f;
  int e = beg;
  for (; e + 1 < end; e += 2) {
    int s0 = col[e], s1 = col[e + 1];
    h4 v0 = *(const h4*)&xws[(size_t)s0 * 128 + c];
    h4 v1 = *(const h4*)&xws[(size_t)s1 * 128 + c];
    a0 += (float)v0[0] + (float)v1[0];
    a1 += (float)v0[1] + (float)v1[1];
    a2 += (float)v0[2] + (float)v1[2];
    a3 += (float)v0[3] + (float)v1[3];
  }
  if (e < end) {
    int s0 = col[e];
    h4 v0 = *(const h4*)&xws[(size_t)s0 * 128 + c];
    a0 += (float)v0[0]; a1 += (float)v0[1];
    a2 += (float)v0[2]; a3 += (float)v0[3];
  }
  float dn = dinv[node];
  h4 self = *(const h4*)&xws[(size_t)node * 128 + c];
  float4 bb = *(const float4*)&b[c];
  h4 o;
  o[0] = (_Float16)fmaxf(fmaf(dn, a0 + (float)self[0], bb.x), 0.0f);
  o[1] = (_Float16)fmaxf(fmaf(dn, a1 + (float)self[1], bb.y), 0.0f);
  o[2] = (_Float16)fmaxf(fmaf(dn, a2 + (float)self[2], bb.z), 0.0f);
  o[3] = (_Float16)fmaxf(fmaf(dn, a3 + (float)self[3], bb.w), 0.0f);
  *(h4*)&h[(size_t)node * 128 + c] = o;
}

// ------- segmented mean-pool (fp16 h): grid (NGRAPH, POOL_RS) -------
__global__ __launch_bounds__(256) void k_pool(const _Float16* __restrict__ h,
                                              const int* __restrict__ gstart,
                                              float* __restrict__ sums) {
  int g = blockIdx.x;
  int rs = blockIdx.y;
  int beg = gstart[g], end = gstart[g + 1];
  int tid = threadIdx.x;
  int ty = tid >> 5;
  int q = (tid & 31) * 4;

  float4 acc; acc.x = acc.y = acc.z = acc.w = 0.0f;
  for (int r = beg + rs * 8 + ty; r < end; r += POOL_RS * 8) {
    h4 v = *(const h4*)&h[(size_t)r * 128 + q];
    acc.x += (float)v[0]; acc.y += (float)v[1];
    acc.z += (float)v[2]; acc.w += (float)v[3];
  }
  __shared__ float s[8][128];
  *(float4*)&s[ty][q] = acc;
  __syncthreads();
  if (tid < 32) {
    int qq = tid * 4;
    float4 t; t.x = t.y = t.z = t.w = 0.0f;
#pragma unroll
    for (int j = 0; j < 8; ++j) {
      float4 v = *(float4*)&s[j][qq];
      t.x += v.x; t.y += v.y; t.z += v.z; t.w += v.w;
    }
    float* base = &sums[g * 128 + qq];
    unsafeAtomicAdd(base + 0, t.x);
    unsafeAtomicAdd(base + 1, t.y);
    unsafeAtomicAdd(base + 2, t.z);
    unsafeAtomicAdd(base + 3, t.w);
  }
}

// ---------------- head ----------------
__global__ __launch_bounds__(640) void k_head(const float* __restrict__ sums,
                                              const int* __restrict__ gstart,
                                              const float* __restrict__ Wc,
                                              const float* __restrict__ bc,
                                              float* __restrict__ out) {
  int t = threadIdx.x;
  int g = t / 10, c = t % 10;
  float cntf = (float)(gstart[g + 1] - gstart[g]);
  float inv = 1.0f / fmaxf(cntf, 1.0f);
  float acc = 0.0f;
  for (int h = 0; h < 128; ++h)
    acc = fmaf(sums[g * 128 + h], Wc[h * 10 + c], acc);
  out[t] = acc * inv + bc[c];
}

extern "C" void kernel_launch(void* const* d_in, const int* in_sizes, int n_in,
                              void* d_out, int out_size, void* d_ws, size_t ws_size,
                              hipStream_t stream) {
  const float* x   = (const float*)d_in[0];
  const int*   ei  = (const int*)d_in[1];
  const int*   bat = (const int*)d_in[2];
  const float* W1  = (const float*)d_in[3];
  const float* b1  = (const float*)d_in[4];
  const float* W2  = (const float*)d_in[5];
  const float* b2  = (const float*)d_in[6];
  const float* W3  = (const float*)d_in[7];
  const float* b3  = (const float*)d_in[8];
  const float* Wc  = (const float*)d_in[9];
  const float* bc  = (const float*)d_in[10];

  const int N = in_sizes[0] / 128;
  const int E = in_sizes[1] / 2;
  const int NP = ((N + 127) / 128) * 128;        // padded rows for MFMA A-loads

  // workspace layout
  char* wsb = (char*)d_ws;
  int*   deg    = (int*)wsb;                      wsb += (size_t)N * 4;
  int*   rowptr = (int*)wsb;                      wsb += (size_t)(N + 1) * 4;
  int*   cursor = (int*)wsb;                      wsb += (size_t)N * 4;
  int*   bsum   = (int*)wsb;                      wsb += 256 * 4;
  float* dinv   = (float*)wsb;                    wsb += (size_t)N * 4;
  int*   col    = (int*)wsb;                      wsb += (size_t)E * 4;
  float* sums   = (float*)wsb;                    wsb += NGRAPH * HDIM * 4;
  int*   gstart = (int*)wsb;                      wsb += (NGRAPH + 1) * 4;
  wsb = (char*)(((size_t)wsb + 255) & ~(size_t)255);
  _Float16* Wt  = (_Float16*)wsb;                 wsb += 3 * 16384 * 2;
  wsb = (char*)(((size_t)wsb + 255) & ~(size_t)255);
  _Float16* XH  = (_Float16*)wsb;                 wsb += (size_t)NP * 128 * 2;
  _Float16* B1  = (_Float16*)wsb;                 wsb += (size_t)NP * 128 * 2;
  _Float16* B2  = (_Float16*)wsb;

  const int nb_N   = (N + 255) / 256;
  const int nb_E   = (E + 255) / 256;
  const int nb_gem = (N + 127) / 128;
  const int nb_gat = (N + 7) / 8;

  // CSR build (once per call, reused for all 3 layers)
  k_zero<<<nb_N, 256, 0, stream>>>(deg, sums, N);
  k_hist<<<nb_E, 256, 0, stream>>>(ei, deg, E);
  k_scan1<<<nb_N, 256, 0, stream>>>(deg, rowptr, bsum, N);
  k_scan2<<<1, 256, 0, stream>>>(bsum, nb_N);
  k_scan3<<<nb_N, 256, 0, stream>>>(deg, rowptr, bsum, cursor, dinv, N, E);
  k_fill<<<nb_E, 256, 0, stream>>>(ei, cursor, col, E);
  k_gbound<<<nb_N, 256, 0, stream>>>(bat, gstart, N);
  k_wt<<<192, 256, 0, stream>>>(W1, W2, W3, Wt);
  k_xh<<<(N * 32 + 255) / 256, 256, 0, stream>>>(x, XH, N);

  const _Float16* in_ptr = XH;
  const float* bl[3] = {b1, b2, b3};
  for (int L = 0; L < 3; ++L) {
    k_mfma<<<nb_gem, 256, 0, stream>>>(in_ptr, Wt + L * 16384, dinv, B1, N);
    k_gather<<<nb_gat, 256, 0, stream>>>(rowptr, col, B1, dinv, bl[L], B2, N);
    in_ptr = B2;
  }

  dim3 pgrid(NGRAPH, POOL_RS);
  k_pool<<<pgrid, 256, 0, stream>>>(B2, gstart, sums);
  k_head<<<1, 640, 0, stream>>>(sums, gstart, Wc, bc, (float*)d_out);
}

// Round 10
// 294.848 us; speedup vs baseline: 2.0232x; 1.3367x over previous
//
#include <hip/hip_runtime.h>

#define NGRAPH 64
#define HDIM 128
#define POOL_RS 8

typedef _Float16 h4 __attribute__((ext_vector_type(4)));
typedef _Float16 h8 __attribute__((ext_vector_type(8)));
typedef float    f4 __attribute__((ext_vector_type(4)));

// ---- fused setup: x->fp16, W1..3 transpose->fp16, deg=0, sums=0, gbound ----
__global__ __launch_bounds__(256) void k_setup(const float* __restrict__ x,
                                               const int* __restrict__ bat,
                                               const float* __restrict__ W1,
                                               const float* __restrict__ W2,
                                               const float* __restrict__ W3,
                                               _Float16* __restrict__ XH,
                                               _Float16* __restrict__ Wt,
                                               int* __restrict__ deg,
                                               float* __restrict__ sums,
                                               int* __restrict__ gstart, int N) {
  int i = blockIdx.x * 256 + threadIdx.x;
  if (i < N * 32) {                       // x (fp32) -> XH (fp16), 4 elems/thread
    float4 v = *(const float4*)&x[(size_t)i * 4];
    h4 o;
    o[0] = (_Float16)v.x; o[1] = (_Float16)v.y;
    o[2] = (_Float16)v.z; o[3] = (_Float16)v.w;
    *(h4*)&XH[(size_t)i * 4] = o;
  }
  if (i < 3 * 16384) {                    // Wt[l][n][k] = fp16(W_l[k][n])
    int l = i >> 14, j = i & 16383;
    int k = j >> 7, n = j & 127;
    const float* W = (l == 0) ? W1 : (l == 1) ? W2 : W3;
    Wt[l * 16384 + n * 128 + k] = (_Float16)W[k * 128 + n];
  }
  if (i < N) {
    deg[i] = 0;
    int b = bat[i];
    int prev = (i == 0) ? -1 : bat[i - 1];
    for (int g = prev + 1; g <= b; ++g) gstart[g] = i;
    if (i == N - 1)
      for (int g = b + 1; g <= NGRAPH; ++g) gstart[g] = N;
  }
  if (i < NGRAPH * HDIM) sums[i] = 0.0f;
}

// ---- degree histogram + per-edge rank (atomic return value) ----
__global__ __launch_bounds__(256) void k_histr(const int* __restrict__ ei,
                                               int* __restrict__ deg,
                                               int* __restrict__ rank, int E) {
  int e = blockIdx.x * 256 + threadIdx.x;
  if (e < E) {
    int r = atomicAdd(&deg[ei[E + e]], 1);
    rank[e] = r;
  }
}

// ---- scan pass 1: per-block exclusive scan of deg ----
__global__ __launch_bounds__(256) void k_scan1(const int* __restrict__ deg,
                                               int* __restrict__ rowptr,
                                               int* __restrict__ bsum, int N) {
  __shared__ int s[256];
  int tid = threadIdx.x;
  int i = blockIdx.x * 256 + tid;
  int v = (i < N) ? deg[i] : 0;
  s[tid] = v;
  __syncthreads();
#pragma unroll
  for (int off = 1; off < 256; off <<= 1) {
    int t = (tid >= off) ? s[tid - off] : 0;
    __syncthreads();
    s[tid] += t;
    __syncthreads();
  }
  if (i < N) rowptr[i] = s[tid] - v;       // block-local exclusive
  if (tid == 255) bsum[blockIdx.x] = s[255];
}

// ---- scan pass 2+3 fused: each block redundantly reduces bsum[0..b); dinv ----
__global__ __launch_bounds__(256) void k_scan23(const int* __restrict__ deg,
                                                int* __restrict__ rowptr,
                                                const int* __restrict__ bsum,
                                                float* __restrict__ dinv,
                                                int N, int E) {
  __shared__ int red[256];
  int b = blockIdx.x, t = threadIdx.x;
  int partial = 0;
  for (int j = t; j < b; j += 256) partial += bsum[j];
  red[t] = partial;
  __syncthreads();
#pragma unroll
  for (int off = 128; off > 0; off >>= 1) {
    if (t < off) red[t] += red[t + off];
    __syncthreads();
  }
  int boff = red[0];
  int i = b * 256 + t;
  if (i < N) {
    rowptr[i] += boff;
    dinv[i] = rsqrtf((float)deg[i] + 1.0f);
  }
  if (i == 0) rowptr[N] = E;
}

// ---- MFMA GEMM body: C[N,128](fp16) = dinv[row]*(A(fp16) @ W) ----
// 256 thr = 4 waves, 128 rows/block; B from LDS (stride 136).
__device__ __forceinline__ void mfma_body(const _Float16* __restrict__ A,
                                          const _Float16* __restrict__ Wt,
                                          const float* __restrict__ dinv,
                                          _Float16* __restrict__ C, int N,
                                          int bid, int tid, _Float16* ws) {
  // stage 128 rows x 128 halves = 2048 16B-chunks; 16 chunks/row
#pragma unroll
  for (int i = 0; i < 8; ++i) {
    int c0 = tid + i * 256;
    int r = c0 >> 4;
    int off = (c0 & 15) * 8;
    *(h8*)&ws[r * 136 + off] = *(const h8*)&Wt[r * 128 + off];
  }
  __syncthreads();

  const int wv = tid >> 6, l = tid & 63;
  const int lm = l & 15, q = l >> 4;
  const int rb = bid * 128 + wv * 32;

  h8 af[2][4];
#pragma unroll
  for (int mt = 0; mt < 2; ++mt) {
    const _Float16* Ap = &A[(size_t)(rb + mt * 16 + lm) * 128];
#pragma unroll
    for (int kc = 0; kc < 4; ++kc)
      af[mt][kc] = *(const h8*)&Ap[kc * 32 + q * 8];
  }

  f4 acc[2][8];
#pragma unroll
  for (int mt = 0; mt < 2; ++mt)
#pragma unroll
    for (int ct = 0; ct < 8; ++ct)
      acc[mt][ct] = (f4){0.0f, 0.0f, 0.0f, 0.0f};

#pragma unroll
  for (int ct = 0; ct < 8; ++ct) {
    h8 bf[4];
#pragma unroll
    for (int kc = 0; kc < 4; ++kc)
      bf[kc] = *(const h8*)&ws[(ct * 16 + lm) * 136 + kc * 32 + q * 8];
#pragma unroll
    for (int mt = 0; mt < 2; ++mt)
#pragma unroll
      for (int kc = 0; kc < 4; ++kc)
        acc[mt][ct] = __builtin_amdgcn_mfma_f32_16x16x32_f16(af[mt][kc], bf[kc],
                                                             acc[mt][ct], 0, 0, 0);
  }

#pragma unroll
  for (int mt = 0; mt < 2; ++mt) {
#pragma unroll
    for (int r = 0; r < 4; ++r) {
      int row = rb + mt * 16 + q * 4 + r;
      if (row < N) {
        float dn = dinv[row];
        _Float16* Cp = &C[(size_t)row * 128 + lm];
#pragma unroll
        for (int ct = 0; ct < 8; ++ct)
          Cp[ct * 16] = (_Float16)(acc[mt][ct][r] * dn);
      }
    }
  }
}

// ---- standalone MFMA GEMM (layers 2,3) ----
__global__ __launch_bounds__(256) void k_mfma(const _Float16* __restrict__ A,
                                              const _Float16* __restrict__ Wt,
                                              const float* __restrict__ dinv,
                                              _Float16* __restrict__ C, int N) {
  __shared__ _Float16 ws[128 * 136];
  mfma_body(A, Wt, dinv, C, N, blockIdx.x, threadIdx.x, ws);
}

// ---- fused: blocks [0,nbg) do mfma layer-1; blocks [nbg,..) do atomic-free fill ----
__global__ __launch_bounds__(256) void k_fill_mfma(const _Float16* __restrict__ A,
                                                   const _Float16* __restrict__ Wt,
                                                   const float* __restrict__ dinv,
                                                   _Float16* __restrict__ C,
                                                   const int* __restrict__ ei,
                                                   const int* __restrict__ rowptr,
                                                   const int* __restrict__ rank,
                                                   int* __restrict__ col,
                                                   int N, int E, int nbg) {
  __shared__ _Float16 ws[128 * 136];
  if ((int)blockIdx.x < nbg) {
    mfma_body(A, Wt, dinv, C, N, blockIdx.x, threadIdx.x, ws);
  } else {
    int e = (blockIdx.x - nbg) * 256 + threadIdx.x;
    if (e < E) {
      int d = ei[E + e];
      col[rowptr[d] + rank[e]] = ei[e];
    }
  }
}

// ---- fused gather (fp16 in/out): h[n] = relu(dinv[n]*(xws[n]+sum xws[src])+b) ----
// half-wave (32 lanes) per node, lane owns 4 cols; 8 nodes/block; 4-edge unroll.
__global__ __launch_bounds__(256) void k_gather(const int* __restrict__ rowptr,
                                                const int* __restrict__ col,
                                                const _Float16* __restrict__ xws,
                                                const float* __restrict__ dinv,
                                                const float* __restrict__ b,
                                                _Float16* __restrict__ h, int N) {
  int node = blockIdx.x * 8 + (threadIdx.x >> 5);
  if (node >= N) return;
  int sl = threadIdx.x & 31;
  int c = sl * 4;
  int beg = rowptr[node], end = rowptr[node + 1];

  float a0 = 0.0f, a1 = 0.0f, a2 = 0.0f, a3 = 0.0f;
  int e = beg;
  for (; e + 3 < end; e += 4) {
    int s0 = col[e], s1 = col[e + 1], s2 = col[e + 2], s3 = col[e + 3];
    h4 v0 = *(const h4*)&xws[(size_t)s0 * 128 + c];
    h4 v1 = *(const h4*)&xws[(size_t)s1 * 128 + c];
    h4 v2 = *(const h4*)&xws[(size_t)s2 * 128 + c];
    h4 v3 = *(const h4*)&xws[(size_t)s3 * 128 + c];
    a0 += ((float)v0[0] + (float)v1[0]) + ((float)v2[0] + (float)v3[0]);
    a1 += ((float)v0[1] + (float)v1[1]) + ((float)v2[1] + (float)v3[1]);
    a2 += ((float)v0[2] + (float)v1[2]) + ((float)v2[2] + (float)v3[2]);
    a3 += ((float)v0[3] + (float)v1[3]) + ((float)v2[3] + (float)v3[3]);
  }
  for (; e < end; ++e) {
    int s0 = col[e];
    h4 v0 = *(const h4*)&xws[(size_t)s0 * 128 + c];
    a0 += (float)v0[0]; a1 += (float)v0[1];
    a2 += (float)v0[2]; a3 += (float)v0[3];
  }
  float dn = dinv[node];
  h4 self = *(const h4*)&xws[(size_t)node * 128 + c];
  float4 bb = *(const float4*)&b[c];
  h4 o;
  o[0] = (_Float16)fmaxf(fmaf(dn, a0 + (float)self[0], bb.x), 0.0f);
  o[1] = (_Float16)fmaxf(fmaf(dn, a1 + (float)self[1], bb.y), 0.0f);
  o[2] = (_Float16)fmaxf(fmaf(dn, a2 + (float)self[2], bb.z), 0.0f);
  o[3] = (_Float16)fmaxf(fmaf(dn, a3 + (float)self[3], bb.w), 0.0f);
  *(h4*)&h[(size_t)node * 128 + c] = o;
}

// ---- segmented mean-pool (fp16 h): grid (NGRAPH, POOL_RS) ----
__global__ __launch_bounds__(256) void k_pool(const _Float16* __restrict__ h,
                                              const int* __restrict__ gstart,
                                              float* __restrict__ sums) {
  int g = blockIdx.x;
  int rs = blockIdx.y;
  int beg = gstart[g], end = gstart[g + 1];
  int tid = threadIdx.x;
  int ty = tid >> 5;
  int q = (tid & 31) * 4;

  float4 acc; acc.x = acc.y = acc.z = acc.w = 0.0f;
  for (int r = beg + rs * 8 + ty; r < end; r += POOL_RS * 8) {
    h4 v = *(const h4*)&h[(size_t)r * 128 + q];
    acc.x += (float)v[0]; acc.y += (float)v[1];
    acc.z += (float)v[2]; acc.w += (float)v[3];
  }
  __shared__ float s[8][128];
  *(float4*)&s[ty][q] = acc;
  __syncthreads();
  if (tid < 32) {
    int qq = tid * 4;
    float4 t; t.x = t.y = t.z = t.w = 0.0f;
#pragma unroll
    for (int j = 0; j < 8; ++j) {
      float4 v = *(float4*)&s[j][qq];
      t.x += v.x; t.y += v.y; t.z += v.z; t.w += v.w;
    }
    float* base = &sums[g * 128 + qq];
    unsafeAtomicAdd(base + 0, t.x);
    unsafeAtomicAdd(base + 1, t.y);
    unsafeAtomicAdd(base + 2, t.z);
    unsafeAtomicAdd(base + 3, t.w);
  }
}

// ---- head ----
__global__ __launch_bounds__(640) void k_head(const float* __restrict__ sums,
                                              const int* __restrict__ gstart,
                                              const float* __restrict__ Wc,
                                              const float* __restrict__ bc,
                                              float* __restrict__ out) {
  int t = threadIdx.x;
  int g = t / 10, c = t % 10;
  float cntf = (float)(gstart[g + 1] - gstart[g]);
  float inv = 1.0f / fmaxf(cntf, 1.0f);
  float acc = 0.0f;
  for (int h = 0; h < 128; ++h)
    acc = fmaf(sums[g * 128 + h], Wc[h * 10 + c], acc);
  out[t] = acc * inv + bc[c];
}

extern "C" void kernel_launch(void* const* d_in, const int* in_sizes, int n_in,
                              void* d_out, int out_size, void* d_ws, size_t ws_size,
                              hipStream_t stream) {
  const float* x   = (const float*)d_in[0];
  const int*   ei  = (const int*)d_in[1];
  const int*   bat = (const int*)d_in[2];
  const float* W1  = (const float*)d_in[3];
  const float* b1  = (const float*)d_in[4];
  const float* W2  = (const float*)d_in[5];
  const float* b2  = (const float*)d_in[6];
  const float* W3  = (const float*)d_in[7];
  const float* b3  = (const float*)d_in[8];
  const float* Wc  = (const float*)d_in[9];
  const float* bc  = (const float*)d_in[10];

  const int N = in_sizes[0] / 128;
  const int E = in_sizes[1] / 2;
  const int NP = ((N + 127) / 128) * 128;        // padded rows for MFMA A-loads

  // workspace layout
  char* wsb = (char*)d_ws;
  int*   deg    = (int*)wsb;                      wsb += (size_t)N * 4;
  int*   rowptr = (int*)wsb;                      wsb += (size_t)(N + 1) * 4;
  int*   bsum   = (int*)wsb;                      wsb += 256 * 4;
  float* dinv   = (float*)wsb;                    wsb += (size_t)N * 4;
  int*   col    = (int*)wsb;                      wsb += (size_t)E * 4;
  int*   rank   = (int*)wsb;                      wsb += (size_t)E * 4;
  float* sums   = (float*)wsb;                    wsb += NGRAPH * HDIM * 4;
  int*   gstart = (int*)wsb;                      wsb += (NGRAPH + 1) * 4;
  wsb = (char*)(((size_t)wsb + 255) & ~(size_t)255);
  _Float16* Wt  = (_Float16*)wsb;                 wsb += 3 * 16384 * 2;
  wsb = (char*)(((size_t)wsb + 255) & ~(size_t)255);
  _Float16* XH  = (_Float16*)wsb;                 wsb += (size_t)NP * 128 * 2;
  _Float16* B1  = (_Float16*)wsb;                 wsb += (size_t)NP * 128 * 2;
  _Float16* B2  = (_Float16*)wsb;

  const int nb_set = (N * 32 + 255) / 256;
  const int nb_N   = (N + 255) / 256;
  const int nb_E   = (E + 255) / 256;
  const int nb_gem = (N + 127) / 128;
  const int nb_gat = (N + 7) / 8;

  k_setup<<<nb_set, 256, 0, stream>>>(x, bat, W1, W2, W3, XH, Wt, deg, sums, gstart, N);
  k_histr<<<nb_E, 256, 0, stream>>>(ei, deg, rank, E);
  k_scan1<<<nb_N, 256, 0, stream>>>(deg, rowptr, bsum, N);
  k_scan23<<<nb_N, 256, 0, stream>>>(deg, rowptr, bsum, dinv, N, E);

  // layer 1 GEMM overlapped with atomic-free CSR fill
  k_fill_mfma<<<nb_gem + nb_E, 256, 0, stream>>>(XH, Wt, dinv, B1,
                                                 ei, rowptr, rank, col, N, E, nb_gem);
  k_gather<<<nb_gat, 256, 0, stream>>>(rowptr, col, B1, dinv, b1, B2, N);

  k_mfma<<<nb_gem, 256, 0, stream>>>(B2, Wt + 16384, dinv, B1, N);
  k_gather<<<nb_gat, 256, 0, stream>>>(rowptr, col, B1, dinv, b2, B2, N);

  k_mfma<<<nb_gem, 256, 0, stream>>>(B2, Wt + 32768, dinv, B1, N);
  k_gather<<<nb_gat, 256, 0, stream>>>(rowptr, col, B1, dinv, b3, B2, N);

  dim3 pgrid(NGRAPH, POOL_RS);
  k_pool<<<pgrid, 256, 0, stream>>>(B2, gstart, sums);
  k_head<<<1, 640, 0, stream>>>(sums, gstart, Wc, bc, (float*)d_out);
}

// Round 11
// 265.713 us; speedup vs baseline: 2.2450x; 1.1096x over previous
//
#include <hip/hip_runtime.h>

#define NGRAPH 64
#define HDIM 128
#define POOL_RS 8

typedef _Float16 h4 __attribute__((ext_vector_type(4)));
typedef _Float16 h8 __attribute__((ext_vector_type(8)));
typedef float    f4 __attribute__((ext_vector_type(4)));
typedef float    f2 __attribute__((ext_vector_type(2)));

// ---- fused setup: x->fp16, W1..3 transpose->fp16, deg=0, sums=0, gbound ----
__global__ __launch_bounds__(256) void k_setup(const float* __restrict__ x,
                                               const int* __restrict__ bat,
                                               const float* __restrict__ W1,
                                               const float* __restrict__ W2,
                                               const float* __restrict__ W3,
                                               _Float16* __restrict__ XH,
                                               _Float16* __restrict__ Wt,
                                               int* __restrict__ deg,
                                               float* __restrict__ sums,
                                               int* __restrict__ gstart, int N) {
  int i = blockIdx.x * 256 + threadIdx.x;
  if (i < N * 32) {                       // x (fp32) -> XH (fp16), 4 elems/thread
    float4 v = *(const float4*)&x[(size_t)i * 4];
    h4 o;
    o[0] = (_Float16)v.x; o[1] = (_Float16)v.y;
    o[2] = (_Float16)v.z; o[3] = (_Float16)v.w;
    *(h4*)&XH[(size_t)i * 4] = o;
  }
  if (i < 3 * 16384) {                    // Wt[l][n][k] = fp16(W_l[k][n])
    int l = i >> 14, j = i & 16383;
    int k = j >> 7, n = j & 127;
    const float* W = (l == 0) ? W1 : (l == 1) ? W2 : W3;
    Wt[l * 16384 + n * 128 + k] = (_Float16)W[k * 128 + n];
  }
  if (i < N) {
    deg[i] = 0;
    int b = bat[i];
    int prev = (i == 0) ? -1 : bat[i - 1];
    for (int g = prev + 1; g <= b; ++g) gstart[g] = i;
    if (i == N - 1)
      for (int g = b + 1; g <= NGRAPH; ++g) gstart[g] = N;
  }
  if (i < NGRAPH * HDIM) sums[i] = 0.0f;
}

// ---- degree histogram + per-edge rank (atomic return value) ----
__global__ __launch_bounds__(256) void k_histr(const int* __restrict__ ei,
                                               int* __restrict__ deg,
                                               int* __restrict__ rank, int E) {
  int e = blockIdx.x * 256 + threadIdx.x;
  if (e < E) {
    int r = atomicAdd(&deg[ei[E + e]], 1);
    rank[e] = r;
  }
}

// ---- scan pass 1: per-block exclusive scan of deg ----
__global__ __launch_bounds__(256) void k_scan1(const int* __restrict__ deg,
                                               int* __restrict__ rowptr,
                                               int* __restrict__ bsum, int N) {
  __shared__ int s[256];
  int tid = threadIdx.x;
  int i = blockIdx.x * 256 + tid;
  int v = (i < N) ? deg[i] : 0;
  s[tid] = v;
  __syncthreads();
#pragma unroll
  for (int off = 1; off < 256; off <<= 1) {
    int t = (tid >= off) ? s[tid - off] : 0;
    __syncthreads();
    s[tid] += t;
    __syncthreads();
  }
  if (i < N) rowptr[i] = s[tid] - v;       // block-local exclusive
  if (tid == 255) bsum[blockIdx.x] = s[255];
}

// ---- scan pass 2+3 fused: each block redundantly reduces bsum[0..b); dinv ----
__global__ __launch_bounds__(256) void k_scan23(const int* __restrict__ deg,
                                                int* __restrict__ rowptr,
                                                const int* __restrict__ bsum,
                                                float* __restrict__ dinv,
                                                int N, int E) {
  __shared__ int red[256];
  int b = blockIdx.x, t = threadIdx.x;
  int partial = 0;
  for (int j = t; j < b; j += 256) partial += bsum[j];
  red[t] = partial;
  __syncthreads();
#pragma unroll
  for (int off = 128; off > 0; off >>= 1) {
    if (t < off) red[t] += red[t + off];
    __syncthreads();
  }
  int boff = red[0];
  int i = b * 256 + t;
  if (i < N) {
    rowptr[i] += boff;
    dinv[i] = rsqrtf((float)deg[i] + 1.0f);
  }
  if (i == 0) rowptr[N] = E;
}

// ---- MFMA GEMM body: C[N,128](fp8 e4m3) = dinv[row]*(A(fp16) @ W) ----
// 256 thr = 4 waves, 128 rows/block; B from LDS (stride 136).
__device__ __forceinline__ void mfma_body(const _Float16* __restrict__ A,
                                          const _Float16* __restrict__ Wt,
                                          const float* __restrict__ dinv,
                                          unsigned char* __restrict__ C, int N,
                                          int bid, int tid, _Float16* ws) {
  // stage 128 rows x 128 halves = 2048 16B-chunks; 16 chunks/row
#pragma unroll
  for (int i = 0; i < 8; ++i) {
    int c0 = tid + i * 256;
    int r = c0 >> 4;
    int off = (c0 & 15) * 8;
    *(h8*)&ws[r * 136 + off] = *(const h8*)&Wt[r * 128 + off];
  }
  __syncthreads();

  const int wv = tid >> 6, l = tid & 63;
  const int lm = l & 15, q = l >> 4;
  const int rb = bid * 128 + wv * 32;

  h8 af[2][4];
#pragma unroll
  for (int mt = 0; mt < 2; ++mt) {
    const _Float16* Ap = &A[(size_t)(rb + mt * 16 + lm) * 128];
#pragma unroll
    for (int kc = 0; kc < 4; ++kc)
      af[mt][kc] = *(const h8*)&Ap[kc * 32 + q * 8];
  }

  f4 acc[2][8];
#pragma unroll
  for (int mt = 0; mt < 2; ++mt)
#pragma unroll
    for (int ct = 0; ct < 8; ++ct)
      acc[mt][ct] = (f4){0.0f, 0.0f, 0.0f, 0.0f};

#pragma unroll
  for (int ct = 0; ct < 8; ++ct) {
    h8 bf[4];
#pragma unroll
    for (int kc = 0; kc < 4; ++kc)
      bf[kc] = *(const h8*)&ws[(ct * 16 + lm) * 136 + kc * 32 + q * 8];
#pragma unroll
    for (int mt = 0; mt < 2; ++mt)
#pragma unroll
      for (int kc = 0; kc < 4; ++kc)
        acc[mt][ct] = __builtin_amdgcn_mfma_f32_16x16x32_f16(af[mt][kc], bf[kc],
                                                             acc[mt][ct], 0, 0, 0);
  }

#pragma unroll
  for (int mt = 0; mt < 2; ++mt) {
#pragma unroll
    for (int r = 0; r < 4; ++r) {
      int row = rb + mt * 16 + q * 4 + r;
      if (row < N) {
        float dn = dinv[row];
        unsigned char* Cp = &C[(size_t)row * 128 + lm];
#pragma unroll
        for (int ct = 0; ct < 8; ++ct) {
          float v = acc[mt][ct][r] * dn;
          unsigned int p = __builtin_amdgcn_cvt_pk_fp8_f32(v, v, 0, false);
          Cp[ct * 16] = (unsigned char)(p & 0xFF);
        }
      }
    }
  }
}

// ---- standalone MFMA GEMM (layers 2,3) ----
__global__ __launch_bounds__(256) void k_mfma(const _Float16* __restrict__ A,
                                              const _Float16* __restrict__ Wt,
                                              const float* __restrict__ dinv,
                                              unsigned char* __restrict__ C, int N) {
  __shared__ _Float16 ws[128 * 136];
  mfma_body(A, Wt, dinv, C, N, blockIdx.x, threadIdx.x, ws);
}

// ---- fused: blocks [0,nbg) do mfma layer-1; blocks [nbg,..) do atomic-free fill ----
__global__ __launch_bounds__(256) void k_fill_mfma(const _Float16* __restrict__ A,
                                                   const _Float16* __restrict__ Wt,
                                                   const float* __restrict__ dinv,
                                                   unsigned char* __restrict__ C,
                                                   const int* __restrict__ ei,
                                                   const int* __restrict__ rowptr,
                                                   const int* __restrict__ rank,
                                                   int* __restrict__ col,
                                                   int N, int E, int nbg) {
  __shared__ _Float16 ws[128 * 136];
  if ((int)blockIdx.x < nbg) {
    mfma_body(A, Wt, dinv, C, N, blockIdx.x, threadIdx.x, ws);
  } else {
    int e = (blockIdx.x - nbg) * 256 + threadIdx.x;
    if (e < E) {
      int d = ei[E + e];
      col[rowptr[d] + rank[e]] = ei[e];
    }
  }
}

// ---- fused gather (fp8 table -> fp16 h): h[n] = relu(dinv[n]*(xws[n]+sum xws[src])+b)
// half-wave (32 lanes) per node, lane owns 4 cols (4B fp8x4 loads); 8 nodes/block.
__global__ __launch_bounds__(256) void k_gather(const int* __restrict__ rowptr,
                                                const int* __restrict__ col,
                                                const unsigned char* __restrict__ xf8,
                                                const float* __restrict__ dinv,
                                                const float* __restrict__ b,
                                                _Float16* __restrict__ h, int N) {
  int node = blockIdx.x * 8 + (threadIdx.x >> 5);
  if (node >= N) return;
  int sl = threadIdx.x & 31;
  int beg = rowptr[node], end = rowptr[node + 1];
  const unsigned int* xw = (const unsigned int*)xf8;   // row stride 32 uints

  float a0 = 0.0f, a1 = 0.0f, a2 = 0.0f, a3 = 0.0f;
  int e = beg;
  for (; e + 3 < end; e += 4) {
    int s0 = col[e], s1 = col[e + 1], s2 = col[e + 2], s3 = col[e + 3];
    unsigned int w0 = xw[(size_t)s0 * 32 + sl];
    unsigned int w1 = xw[(size_t)s1 * 32 + sl];
    unsigned int w2 = xw[(size_t)s2 * 32 + sl];
    unsigned int w3 = xw[(size_t)s3 * 32 + sl];
    f2 l0 = __builtin_amdgcn_cvt_pk_f32_fp8((int)w0, false);
    f2 h0 = __builtin_amdgcn_cvt_pk_f32_fp8((int)w0, true);
    f2 l1 = __builtin_amdgcn_cvt_pk_f32_fp8((int)w1, false);
    f2 h1 = __builtin_amdgcn_cvt_pk_f32_fp8((int)w1, true);
    f2 l2 = __builtin_amdgcn_cvt_pk_f32_fp8((int)w2, false);
    f2 h2 = __builtin_amdgcn_cvt_pk_f32_fp8((int)w2, true);
    f2 l3 = __builtin_amdgcn_cvt_pk_f32_fp8((int)w3, false);
    f2 h3 = __builtin_amdgcn_cvt_pk_f32_fp8((int)w3, true);
    a0 += (l0[0] + l1[0]) + (l2[0] + l3[0]);
    a1 += (l0[1] + l1[1]) + (l2[1] + l3[1]);
    a2 += (h0[0] + h1[0]) + (h2[0] + h3[0]);
    a3 += (h0[1] + h1[1]) + (h2[1] + h3[1]);
  }
  for (; e < end; ++e) {
    unsigned int w0 = xw[(size_t)col[e] * 32 + sl];
    f2 l0 = __builtin_amdgcn_cvt_pk_f32_fp8((int)w0, false);
    f2 h0 = __builtin_amdgcn_cvt_pk_f32_fp8((int)w0, true);
    a0 += l0[0]; a1 += l0[1]; a2 += h0[0]; a3 += h0[1];
  }
  float dn = dinv[node];
  unsigned int wsf = xw[(size_t)node * 32 + sl];
  f2 sl0 = __builtin_amdgcn_cvt_pk_f32_fp8((int)wsf, false);
  f2 sh0 = __builtin_amdgcn_cvt_pk_f32_fp8((int)wsf, true);
  int c = sl * 4;
  float4 bb = *(const float4*)&b[c];
  h4 o;
  o[0] = (_Float16)fmaxf(fmaf(dn, a0 + sl0[0], bb.x), 0.0f);
  o[1] = (_Float16)fmaxf(fmaf(dn, a1 + sl0[1], bb.y), 0.0f);
  o[2] = (_Float16)fmaxf(fmaf(dn, a2 + sh0[0], bb.z), 0.0f);
  o[3] = (_Float16)fmaxf(fmaf(dn, a3 + sh0[1], bb.w), 0.0f);
  *(h4*)&h[(size_t)node * 128 + c] = o;
}

// ---- segmented mean-pool (fp16 h): grid (NGRAPH, POOL_RS) ----
__global__ __launch_bounds__(256) void k_pool(const _Float16* __restrict__ h,
                                              const int* __restrict__ gstart,
                                              float* __restrict__ sums) {
  int g = blockIdx.x;
  int rs = blockIdx.y;
  int beg = gstart[g], end = gstart[g + 1];
  int tid = threadIdx.x;
  int ty = tid >> 5;
  int q = (tid & 31) * 4;

  float4 acc; acc.x = acc.y = acc.z = acc.w = 0.0f;
  for (int r = beg + rs * 8 + ty; r < end; r += POOL_RS * 8) {
    h4 v = *(const h4*)&h[(size_t)r * 128 + q];
    acc.x += (float)v[0]; acc.y += (float)v[1];
    acc.z += (float)v[2]; acc.w += (float)v[3];
  }
  __shared__ float s[8][128];
  *(float4*)&s[ty][q] = acc;
  __syncthreads();
  if (tid < 32) {
    int qq = tid * 4;
    float4 t; t.x = t.y = t.z = t.w = 0.0f;
#pragma unroll
    for (int j = 0; j < 8; ++j) {
      float4 v = *(float4*)&s[j][qq];
      t.x += v.x; t.y += v.y; t.z += v.z; t.w += v.w;
    }
    float* base = &sums[g * 128 + qq];
    unsafeAtomicAdd(base + 0, t.x);
    unsafeAtomicAdd(base + 1, t.y);
    unsafeAtomicAdd(base + 2, t.z);
    unsafeAtomicAdd(base + 3, t.w);
  }
}

// ---- head ----
__global__ __launch_bounds__(640) void k_head(const float* __restrict__ sums,
                                              const int* __restrict__ gstart,
                                              const float* __restrict__ Wc,
                                              const float* __restrict__ bc,
                                              float* __restrict__ out) {
  int t = threadIdx.x;
  int g = t / 10, c = t % 10;
  float cntf = (float)(gstart[g + 1] - gstart[g]);
  float inv = 1.0f / fmaxf(cntf, 1.0f);
  float acc = 0.0f;
  for (int h = 0; h < 128; ++h)
    acc = fmaf(sums[g * 128 + h], Wc[h * 10 + c], acc);
  out[t] = acc * inv + bc[c];
}

extern "C" void kernel_launch(void* const* d_in, const int* in_sizes, int n_in,
                              void* d_out, int out_size, void* d_ws, size_t ws_size,
                              hipStream_t stream) {
  const float* x   = (const float*)d_in[0];
  const int*   ei  = (const int*)d_in[1];
  const int*   bat = (const int*)d_in[2];
  const float* W1  = (const float*)d_in[3];
  const float* b1  = (const float*)d_in[4];
  const float* W2  = (const float*)d_in[5];
  const float* b2  = (const float*)d_in[6];
  const float* W3  = (const float*)d_in[7];
  const float* b3  = (const float*)d_in[8];
  const float* Wc  = (const float*)d_in[9];
  const float* bc  = (const float*)d_in[10];

  const int N = in_sizes[0] / 128;
  const int E = in_sizes[1] / 2;
  const int NP = ((N + 127) / 128) * 128;        // padded rows for MFMA A-loads

  // workspace layout
  char* wsb = (char*)d_ws;
  int*   deg    = (int*)wsb;                      wsb += (size_t)N * 4;
  int*   rowptr = (int*)wsb;                      wsb += (size_t)(N + 1) * 4;
  int*   bsum   = (int*)wsb;                      wsb += 256 * 4;
  float* dinv   = (float*)wsb;                    wsb += (size_t)N * 4;
  int*   col    = (int*)wsb;                      wsb += (size_t)E * 4;
  int*   rank   = (int*)wsb;                      wsb += (size_t)E * 4;
  float* sums   = (float*)wsb;                    wsb += NGRAPH * HDIM * 4;
  int*   gstart = (int*)wsb;                      wsb += (NGRAPH + 1) * 4;
  wsb = (char*)(((size_t)wsb + 255) & ~(size_t)255);
  _Float16* Wt  = (_Float16*)wsb;                 wsb += 3 * 16384 * 2;
  wsb = (char*)(((size_t)wsb + 255) & ~(size_t)255);
  _Float16* XH  = (_Float16*)wsb;                 wsb += (size_t)NP * 128 * 2;
  unsigned char* B1 = (unsigned char*)wsb;        wsb += (size_t)NP * 128;     // fp8 table
  wsb = (char*)(((size_t)wsb + 255) & ~(size_t)255);
  _Float16* B2  = (_Float16*)wsb;

  const int nb_set = (N * 32 + 255) / 256;
  const int nb_N   = (N + 255) / 256;
  const int nb_E   = (E + 255) / 256;
  const int nb_gem = (N + 127) / 128;
  const int nb_gat = (N + 7) / 8;

  k_setup<<<nb_set, 256, 0, stream>>>(x, bat, W1, W2, W3, XH, Wt, deg, sums, gstart, N);
  k_histr<<<nb_E, 256, 0, stream>>>(ei, deg, rank, E);
  k_scan1<<<nb_N, 256, 0, stream>>>(deg, rowptr, bsum, N);
  k_scan23<<<nb_N, 256, 0, stream>>>(deg, rowptr, bsum, dinv, N, E);

  // layer 1 GEMM overlapped with atomic-free CSR fill
  k_fill_mfma<<<nb_gem + nb_E, 256, 0, stream>>>(XH, Wt, dinv, B1,
                                                 ei, rowptr, rank, col, N, E, nb_gem);
  k_gather<<<nb_gat, 256, 0, stream>>>(rowptr, col, B1, dinv, b1, B2, N);

  k_mfma<<<nb_gem, 256, 0, stream>>>(B2, Wt + 16384, dinv, B1, N);
  k_gather<<<nb_gat, 256, 0, stream>>>(rowptr, col, B1, dinv, b2, B2, N);

  k_mfma<<<nb_gem, 256, 0, stream>>>(B2, Wt + 32768, dinv, B1, N);
  k_gather<<<nb_gat, 256, 0, stream>>>(rowptr, col, B1, dinv, b3, B2, N);

  dim3 pgrid(NGRAPH, POOL_RS);
  k_pool<<<pgrid, 256, 0, stream>>>(B2, gstart, sums);
  k_head<<<1, 640, 0, stream>>>(sums, gstart, Wc, bc, (float*)d_out);
}